// Round 7
// baseline (5841.500 us; speedup 1.0000x reference)
//
#include <hip/hip_runtime.h>
#include <cstdint>

#define TT 512

typedef float f32x16 __attribute__((ext_vector_type(16)));
typedef short s16x8 __attribute__((ext_vector_type(8)));
typedef unsigned short u16x4 __attribute__((ext_vector_type(4)));

// ---------------- threefry2x32 (exact JAX semantics) ----------------
__host__ __device__ inline void tf2x32(uint32_t k0, uint32_t k1, uint32_t& x0, uint32_t& x1) {
  uint32_t k2 = k0 ^ k1 ^ 0x1BD11BDAu;
#define TF_R(r) { x0 += x1; x1 = (x1 << r) | (x1 >> (32 - r)); x1 ^= x0; }
  x0 += k0; x1 += k1;
  TF_R(13) TF_R(15) TF_R(26) TF_R(6)
  x0 += k1; x1 += k2 + 1u;
  TF_R(17) TF_R(29) TF_R(16) TF_R(24)
  x0 += k2; x1 += k0 + 2u;
  TF_R(13) TF_R(15) TF_R(26) TF_R(6)
  x0 += k0; x1 += k1 + 3u;
  TF_R(17) TF_R(29) TF_R(16) TF_R(24)
  x0 += k1; x1 += k2 + 4u;
  TF_R(13) TF_R(15) TF_R(26) TF_R(6)
  x0 += k2; x1 += k0 + 5u;
#undef TF_R
}

struct KParams {
  const float* input;
  const float* w_ih[4];
  const float* w_hh[4];
  const float* b_ih[4];
  const float* b_hh[4];
  const float* w_lin;
  const float* b_lin;
  unsigned short* hLLC;   // [8][2][32768] bf16 — LLC-coherent copy (sc0 sc1)
  unsigned short* hL2;    // [8][2][32768] bf16 — per-XCD L2 copy (sc0), data only
  uint32_t* fLLC;         // [8][64][32] epoch-ring flags, value = t+1 (LLC, R5-proven)
  uint32_t* fL2;          // [8][8][32] own-edge epoch flags (XCD-local L2, atomic-read)
  uint32_t* xcdtab;       // [256]
  uint32_t* initcnt;      // [1]
  float* out;             // [128][512]
  uint32_t mk[4][2];      // per-layer threefry subkeys (partitionable split)
};

__device__ __forceinline__ unsigned short f2bf(float v) {
  uint32_t u = __float_as_uint(v);
  u += 0x7FFFu + ((u >> 16) & 1u);      // RNE
  return (unsigned short)(u >> 16);
}
__device__ __forceinline__ float bf2f(unsigned short b) {
  return __uint_as_float(((uint32_t)b) << 16);
}
__device__ __forceinline__ float sigm(float x) { return 1.f / (1.f + __expf(-x)); }
__device__ __forceinline__ float tanh_fast(float x) {
  float a = fabsf(x);
  float e = __expf(-2.f * a);
  float r = (1.f - e) / (1.f + e);
  return copysignf(r, x);
}

#define MFMA(A, Bv, C) __builtin_amdgcn_mfma_f32_32x32x16_bf16((A), (Bv), (C), 0, 0, 0)

// counted vmcnt wait (a = pipeline iterations still allowed in flight; 2 loads/iter)
__device__ __forceinline__ void vmwait_dyn(int a) {
  switch (a) {
    case 0: asm volatile("s_waitcnt vmcnt(0)" ::: "memory"); break;
    case 1: asm volatile("s_waitcnt vmcnt(2)" ::: "memory"); break;
    case 2: asm volatile("s_waitcnt vmcnt(4)" ::: "memory"); break;
    case 3: asm volatile("s_waitcnt vmcnt(6)" ::: "memory"); break;
    case 4: asm volatile("s_waitcnt vmcnt(8)" ::: "memory"); break;
    case 5: asm volatile("s_waitcnt vmcnt(10)" ::: "memory"); break;
    case 6: asm volatile("s_waitcnt vmcnt(12)" ::: "memory"); break;
    case 7: asm volatile("s_waitcnt vmcnt(14)" ::: "memory"); break;
    default: asm volatile("s_waitcnt vmcnt(16)" ::: "memory"); break;
  }
  __builtin_amdgcn_sched_barrier(0);
}

#define ISSUE_LLC(s0, s1, ptr) \
  asm volatile("global_load_dwordx4 %0, %2, off sc0 sc1\n\t" \
               "global_load_dwordx4 %1, %2, off offset:1024 sc0 sc1" \
               : "=&v"(s0), "=&v"(s1) : "v"(ptr) : "memory")
#define ISSUE_L2(s0, s1, ptr) \
  asm volatile("global_load_dwordx4 %0, %2, off sc0\n\t" \
               "global_load_dwordx4 %1, %2, off offset:1024 sc0" \
               : "=&v"(s0), "=&v"(s1) : "v"(ptr) : "memory")

// frag i < OWNSTART comes from bufB (always LLC); i >= OWNSTART from bufO (L2 iff OWNL2)
template <int NIT, int OWNSTART, bool OWNL2>
__device__ __forceinline__ void run_gemm(const unsigned short* bufB, const unsigned short* bufO,
                                         const s16x8 (&Whi)[2][16], const s16x8 (&Wlo)[2][16],
                                         int wave, int lane,
                                         f32x16& a00, f32x16& a01, f32x16& a10, f32x16& a11) {
  constexpr int D = 8;
  constexpr int S = D + 1;
  s16x8 st[S][2];
  const int lofs = wave * 1024 + lane * 8;   // blk = (i&7)*4 + wave
#pragma unroll
  for (int i = 0; i < ((NIT < D) ? NIT : D); ++i) {
    const unsigned short* ptr = ((i >= OWNSTART) ? bufO : bufB) + (i & 7) * 4096 + lofs;
    if (i >= OWNSTART && OWNL2) { ISSUE_L2(st[i % S][0], st[i % S][1], ptr); }
    else                        { ISSUE_LLC(st[i % S][0], st[i % S][1], ptr); }
  }
#pragma unroll
  for (int i = 0; i < NIT; ++i) {
    if (i + D < NIT) {
      const int k = i + D;
      const unsigned short* ptr = ((k >= OWNSTART) ? bufO : bufB) + (k & 7) * 4096 + lofs;
      if (k >= OWNSTART && OWNL2) { ISSUE_L2(st[k % S][0], st[k % S][1], ptr); }
      else                        { ISSUE_LLC(st[k % S][0], st[k % S][1], ptr); }
    }
    vmwait_dyn((NIT - 1 - i < D) ? (NIT - 1 - i) : D);
    s16x8 bh0 = st[i % S][0];
    s16x8 bh1 = st[i % S][1];
    a00 = MFMA(Whi[0][i], bh0, a00);
    a10 = MFMA(Whi[1][i], bh0, a10);
    a01 = MFMA(Whi[0][i], bh1, a01);
    a11 = MFMA(Whi[1][i], bh1, a11);
    a00 = MFMA(Wlo[0][i], bh0, a00);
    a10 = MFMA(Wlo[1][i], bh0, a10);
    a01 = MFMA(Wlo[0][i], bh1, a01);
    a11 = MFMA(Wlo[1][i], bh1, a11);
  }
}

// epoch-ring wait via LLC agent atomic (R5-proven; guaranteed progress)
__device__ __forceinline__ void pollLLC(const uint32_t* fp, uint32_t want, int lane) {
  while (true) {
    uint32_t v = __hip_atomic_load(fp + (lane & 31), __ATOMIC_RELAXED, __HIP_MEMORY_SCOPE_AGENT);
    if (__all(v >= want)) break;
    __builtin_amdgcn_s_sleep(1);
  }
}
// bounded XCD-local wait: workgroup-scope atomic RMW executes at the local L2 (never L1)
__device__ __forceinline__ bool pollL2b(uint32_t* fp, uint32_t want, int lane) {
  for (int it = 0; it < (1 << 13); ++it) {
    uint32_t v = __hip_atomic_fetch_add(fp + (lane & 31), 0u,
                                        __ATOMIC_RELAXED, __HIP_MEMORY_SCOPE_WORKGROUP);
    if (__all(v >= want)) return true;
    __builtin_amdgcn_s_sleep(1);
  }
  return false;
}

__global__ __launch_bounds__(256, 1) void lstm4(KParams P) {
  const int wg   = blockIdx.x;
  const int grp  = wg & 7;       // (layer, half) — one XCD per group under round-robin
  const int iwg  = wg >> 3;      // 0..31: which 16-unit slice
  const int l    = grp >> 1;
  const int p    = grp & 1;
  const int tid  = threadIdx.x;
  const int wave = tid >> 6;
  const int lane = tid & 63;

  __shared__ float part[4][64][64];   // 64 KB: per-wave k-split partials, single phase
  __shared__ float bias_s[64];
  __shared__ float wih1_s[64];
  __shared__ float wlin_s[16];
  __shared__ float red_s[4][64];
  __shared__ uint32_t xs[8];
  __shared__ uint32_t barflag;

  // ---- XCD identity probe (hwreg 20 = XCC_ID; wrong field -> check fails -> LLC fallback)
  uint32_t xcd;
  asm volatile("s_getreg_b32 %0, hwreg(20, 0, 4)" : "=s"(xcd));

  // ---- clear this group's fL2 slots IN the local L2 (kills stale dirty lines from replays)
  if (tid < 8 * 32) {   // 8 slots x 32 flags for this group
    uint32_t* cp = P.fL2 + (size_t)grp * 8 * 32 + tid;
    uint32_t z = 0u;
    asm volatile("global_store_dword %0, %1, off sc0" :: "v"(cp), "v"(z) : "memory");
  }
  asm volatile("s_waitcnt vmcnt(0)" ::: "memory");
  __syncthreads();

  if (tid == 0) {
    __hip_atomic_store(&P.xcdtab[wg], xcd, __ATOMIC_RELAXED, __HIP_MEMORY_SCOPE_AGENT);
    asm volatile("s_waitcnt vmcnt(0)" ::: "memory");
    __hip_atomic_fetch_add(P.initcnt, 1u, __ATOMIC_RELAXED, __HIP_MEMORY_SCOPE_AGENT);
  }

  // ---- weight fragments (hi + lo bf16) into registers (overlaps other WGs' init)
  s16x8 Whi[2][16], Wlo[2][16];
  {
#pragma unroll
    for (int ji = 0; ji < 16; ++ji) {
      const bool valid = (l > 0) || (ji < 8);
      const float* wsrc = (l == 0 || ji >= 8) ? P.w_hh[l] : P.w_ih[l];
      const int blk = (ji & 7) * 4 + wave;
      const int col = blk * 16 + (lane >> 5) * 8;
#pragma unroll
      for (int m = 0; m < 2; ++m) {
        const int rl = m * 32 + (lane & 31);
        const int grow = (rl >> 4) * 512 + iwg * 16 + (rl & 15);
        s16x8 h8 = {0, 0, 0, 0, 0, 0, 0, 0};
        s16x8 l8 = {0, 0, 0, 0, 0, 0, 0, 0};
        if (valid) {
          const float* s = wsrc + grow * 512 + col;
#pragma unroll
          for (int e = 0; e < 8; ++e) {
            float v = s[e];
            unsigned short hb = f2bf(v);
            h8[e] = (short)hb;
            l8[e] = (short)f2bf(v - bf2f(hb));
          }
        }
        Whi[m][ji] = h8;
        Wlo[m][ji] = l8;
      }
    }
  }
  if (tid < 64) {
    const int rl = tid;
    const int grow = (rl >> 4) * 512 + iwg * 16 + (rl & 15);
    bias_s[rl] = P.b_ih[l][grow] + P.b_hh[l][grow];
    wih1_s[rl] = (l == 0) ? P.w_ih[0][grow] : 0.f;
  }
  if (l == 3 && tid < 16) wlin_s[tid] = P.w_lin[iwg * 16 + tid];

  // ---- bounded grid init barrier (timeout -> LLC-only fallback, never hang)
  if (tid == 0) {
    uint32_t okv = 1u, tries = 0u;
    while (__hip_atomic_load(P.initcnt, __ATOMIC_RELAXED, __HIP_MEMORY_SCOPE_AGENT) < 256u) {
      __builtin_amdgcn_s_sleep(8);
      if (++tries > (1u << 17)) { okv = 0u; break; }
    }
    barflag = okv;
  }
  __syncthreads();
  const bool bar_ok = (barflag != 0u);

  // ---- XCD-mapping verification
  uint32_t va = __hip_atomic_load(&P.xcdtab[tid], __ATOMIC_RELAXED, __HIP_MEMORY_SCOPE_AGENT);
  uint32_t vb = __hip_atomic_load(&P.xcdtab[tid & 7], __ATOMIC_RELAXED, __HIP_MEMORY_SCOPE_AGENT);
  int ok1 = __syncthreads_and((va == vb) ? 1 : 0);
  if (tid < 8) xs[tid] = vb;
  __syncthreads();
  bool dis = true;
#pragma unroll
  for (int a = 0; a < 8; ++a)
#pragma unroll
    for (int b = a + 1; b < 8; ++b)
      if (xs[a] == xs[b]) dis = false;
  const bool l2ok = bar_ok && (ok1 != 0) && dis;
  __syncthreads();

  const int gb = p * 64 + lane;
  const uint32_t kk0 = P.mk[l][0], kk1 = P.mk[l][1];
  float cst[4] = {0.f, 0.f, 0.f, 0.f};
  bool l2live = l2ok;   // sticky: wave1 drops to LLC polling after any bounded-poll timeout

  for (int t = 0; t < TT; ++t) {
    float xin = 0.f;
    if (l == 0) xin = P.input[gb * 512 + t];

    // ---------- waits: wave0=below(t) LLC, wave1=own(t-1) L2-atomic->LLC, wave2=above(t-2) LLC ----------
    if (wave == 0 && l > 0) {
      pollLLC(P.fLLC + ((size_t)((l - 1) * 2 + p) * 64 + (t & 63)) * 32, (uint32_t)(t + 1), lane);
    } else if (wave == 1 && t > 0) {
      bool seen = false;
      if (l2live) {
        seen = pollL2b(P.fL2 + ((size_t)grp * 8 + ((t - 1) & 7)) * 32, (uint32_t)t, lane);
        if (!seen) l2live = false;
      }
      if (!seen)
        pollLLC(P.fLLC + ((size_t)grp * 64 + ((t - 1) & 63)) * 32, (uint32_t)t, lane);
    } else if (wave == 2 && l < 3 && t >= 2) {
      pollLLC(P.fLLC + ((size_t)((l + 1) * 2 + p) * 64 + ((t - 2) & 63)) * 32, (uint32_t)(t - 1), lane);
    }
    __syncthreads();
    asm volatile("s_waitcnt vmcnt(0)" ::: "memory");   // drain xin/polls: counted waits exact

    // ---------- GEMM ----------
    f32x16 a00 = {0,0,0,0,0,0,0,0,0,0,0,0,0,0,0,0};
    f32x16 a01 = {0,0,0,0,0,0,0,0,0,0,0,0,0,0,0,0};
    f32x16 a10 = {0,0,0,0,0,0,0,0,0,0,0,0,0,0,0,0};
    f32x16 a11 = {0,0,0,0,0,0,0,0,0,0,0,0,0,0,0,0};

    const unsigned short* pB    = P.hLLC + (size_t)(((l - 1) * 2 + p) * 2 + (t & 1)) * 32768;
    const unsigned short* pOL2  = P.hL2  + (size_t)(grp * 2 + ((t - 1) & 1)) * 32768;
    const unsigned short* pOLLC = P.hLLC + (size_t)(grp * 2 + ((t - 1) & 1)) * 32768;

    if (l > 0) {
      if (t > 0) {
        if (l2ok) run_gemm<16, 8, true >(pB, pOL2,  Whi, Wlo, wave, lane, a00, a01, a10, a11);
        else      run_gemm<16, 8, false>(pB, pOLLC, Whi, Wlo, wave, lane, a00, a01, a10, a11);
      } else {
        run_gemm<8, 8, false>(pB, pB, Whi, Wlo, wave, lane, a00, a01, a10, a11);
      }
    } else if (t > 0) {
      if (l2ok) run_gemm<8, 0, true >(pOL2,  pOL2,  Whi, Wlo, wave, lane, a00, a01, a10, a11);
      else      run_gemm<8, 0, false>(pOLLC, pOLLC, Whi, Wlo, wave, lane, a00, a01, a10, a11);
    }

    // ---------- single-phase cross-wave k-split reduction ----------
#pragma unroll
    for (int r = 0; r < 16; ++r) {
      const int row = (r & 3) + 8 * (r >> 2) + 4 * (lane >> 5);
      const int cl = lane & 31;
      part[wave][row][cl]           = a00[r];
      part[wave][row][32 + cl]      = a01[r];
      part[wave][32 + row][cl]      = a10[r];
      part[wave][32 + row][32 + cl] = a11[r];
    }

    // dropout factors (threefry) in the barrier shadow
    float fac[4];
#pragma unroll
    for (int cc = 0; cc < 4; ++cc) {
      const int gu = iwg * 16 + wave * 4 + cc;
      uint32_t j = ((uint32_t)t * 128u + (uint32_t)gb) * 512u + (uint32_t)gu;
      uint32_t x0 = 0u, x1 = j;
      tf2x32(kk0, kk1, x0, x1);
      fac[cc] = ((x0 ^ x1) & 0x80000000u) ? 0.f : 2.f;
    }
    __syncthreads();

    float si[4], sf[4], sg[4], so[4];
#pragma unroll
    for (int cc = 0; cc < 4; ++cc) {
      const int ul = wave * 4 + cc;
      si[cc] = part[0][ul][lane]      + part[1][ul][lane]      + part[2][ul][lane]      + part[3][ul][lane];
      sf[cc] = part[0][16 + ul][lane] + part[1][16 + ul][lane] + part[2][16 + ul][lane] + part[3][16 + ul][lane];
      sg[cc] = part[0][32 + ul][lane] + part[1][32 + ul][lane] + part[2][32 + ul][lane] + part[3][32 + ul][lane];
      so[cc] = part[0][48 + ul][lane] + part[1][48 + ul][lane] + part[2][48 + ul][lane] + part[3][48 + ul][lane];
    }

    // ---------- elementwise LSTM cell ----------
    float osum = 0.f;
    u16x4 hv;
#pragma unroll
    for (int cc = 0; cc < 4; ++cc) {
      const int ul = wave * 4 + cc;
      float pi = si[cc] + bias_s[ul];
      float pf = sf[cc] + bias_s[16 + ul];
      float pg = sg[cc] + bias_s[32 + ul];
      float po = so[cc] + bias_s[48 + ul];
      if (l == 0) {
        pi += wih1_s[ul] * xin;
        pf += wih1_s[16 + ul] * xin;
        pg += wih1_s[32 + ul] * xin;
        po += wih1_s[48 + ul] * xin;
      }
      float ig = sigm(pi), fg = sigm(pf), gg = tanh_fast(pg), og = sigm(po);
      float cn = fg * cst[cc] + ig * gg;
      cst[cc] = cn;
      float hh = og * tanh_fast(cn) * fac[cc];
      hv[cc] = f2bf(hh);
      if (l == 3) osum += hh * wlin_s[ul];
    }

    // ---------- unconditional dual h store (LLC + per-XCD L2) + dual publish ----------
    {
      const int elem = ((iwg * 2 + (lane >> 5)) * 64 + (wave >> 1) * 32 + (lane & 31)) * 8 + (wave & 1) * 4;
      unsigned short* wLLC = P.hLLC + (size_t)(grp * 2 + (t & 1)) * 32768 + elem;
      unsigned short* wL2  = P.hL2  + (size_t)(grp * 2 + (t & 1)) * 32768 + elem;
      asm volatile("global_store_dwordx2 %0, %1, off sc0 sc1" :: "v"(wLLC), "v"(hv) : "memory");
      asm volatile("global_store_dwordx2 %0, %1, off sc0" :: "v"(wL2), "v"(hv) : "memory");
      asm volatile("s_waitcnt vmcnt(0)" ::: "memory");
    }
    __syncthreads();
    if (tid == 0) {
      // XCD-local flag first (fast visibility to same-XCD consumers)...
      uint32_t* fp2 = P.fL2 + ((size_t)grp * 8 + (t & 7)) * 32 + iwg;
      uint32_t v = (uint32_t)(t + 1);
      asm volatile("global_store_dword %0, %1, off sc0" :: "v"(fp2), "v"(v) : "memory");
      // ...then the LLC copy (fallback path + R5-proven protocol)
      __hip_atomic_store(P.fLLC + ((size_t)grp * 64 + (t & 63)) * 32 + iwg, v,
                         __ATOMIC_RELAXED, __HIP_MEMORY_SCOPE_AGENT);
    }

    // ---------- layer-3 projection (after publish) ----------
    if (l == 3) {
      red_s[wave][lane] = osum;
      __syncthreads();
      if (tid < 64) {
        float v = red_s[0][tid] + red_s[1][tid] + red_s[2][tid] + red_s[3][tid];
        if (iwg == 0) v += P.b_lin[0];
        atomicAdd(&P.out[(p * 64 + tid) * 512 + t], v);
      }
    }
  }
}

extern "C" void kernel_launch(void* const* d_in, const int* in_sizes, int n_in,
                              void* d_out, int out_size, void* d_ws, size_t ws_size,
                              hipStream_t stream) {
  (void)in_sizes; (void)n_in; (void)ws_size;
  KParams P;
  P.input = (const float*)d_in[0];
  for (int l = 0; l < 4; ++l) {
    P.w_ih[l] = (const float*)d_in[1 + 4 * l];
    P.w_hh[l] = (const float*)d_in[2 + 4 * l];
    P.b_ih[l] = (const float*)d_in[3 + 4 * l];
    P.b_hh[l] = (const float*)d_in[4 + 4 * l];
  }
  P.w_lin = (const float*)d_in[17];
  P.b_lin = (const float*)d_in[18];
  unsigned char* ws = (unsigned char*)d_ws;
  P.hLLC    = (unsigned short*)(ws);                          // 1 MB   [8][2][32768]
  P.hL2     = (unsigned short*)(ws + (1u << 20));             // 1 MB   [8][2][32768]
  P.fLLC    = (uint32_t*)(ws + (2u << 20));                   // 64 KB  [8][64][32]
  P.xcdtab  = (uint32_t*)(ws + (2u << 20) + (64u << 10));     // 1 KB
  P.initcnt = (uint32_t*)(ws + (2u << 20) + (64u << 10) + 1024);
  P.fL2     = (uint32_t*)(ws + (2u << 20) + (68u << 10));     // 8 KB   [8][8][32]
  P.out     = (float*)d_out;
  // total ws span ~2.07 MB (<= 2.62 MB proven by R2/R3)

  // subkeys = jax.random.split(key(42), 4) under threefry_partitionable=True
  for (uint32_t i = 0; i < 4; ++i) {
    uint32_t x0 = 0u, x1 = i;
    tf2x32(0u, 42u, x0, x1);
    P.mk[i][0] = x0; P.mk[i][1] = x1;
  }

  hipMemsetAsync(P.fLLC, 0, 8 * 64 * 32 * sizeof(uint32_t), stream);
  hipMemsetAsync(P.xcdtab, 0, 2048, stream);                  // xcdtab + initcnt
  hipMemsetAsync(P.fL2, 0, 8 * 8 * 32 * sizeof(uint32_t), stream);
  hipMemsetAsync(d_out, 0, (size_t)out_size * sizeof(float), stream);
  hipLaunchKernelGGL(lstm4, dim3(256), dim3(256), 0, stream, P);
}

// Round 8
// 3200.983 us; speedup vs baseline: 1.8249x; 1.8249x over previous
//
#include <hip/hip_runtime.h>
#include <cstdint>

#define TT 512

typedef float f32x16 __attribute__((ext_vector_type(16)));
typedef short s16x8 __attribute__((ext_vector_type(8)));
typedef unsigned short u16x4 __attribute__((ext_vector_type(4)));

// ---------------- threefry2x32 (exact JAX semantics) ----------------
__host__ __device__ inline void tf2x32(uint32_t k0, uint32_t k1, uint32_t& x0, uint32_t& x1) {
  uint32_t k2 = k0 ^ k1 ^ 0x1BD11BDAu;
#define TF_R(r) { x0 += x1; x1 = (x1 << r) | (x1 >> (32 - r)); x1 ^= x0; }
  x0 += k0; x1 += k1;
  TF_R(13) TF_R(15) TF_R(26) TF_R(6)
  x0 += k1; x1 += k2 + 1u;
  TF_R(17) TF_R(29) TF_R(16) TF_R(24)
  x0 += k2; x1 += k0 + 2u;
  TF_R(13) TF_R(15) TF_R(26) TF_R(6)
  x0 += k0; x1 += k1 + 3u;
  TF_R(17) TF_R(29) TF_R(16) TF_R(24)
  x0 += k1; x1 += k2 + 4u;
  TF_R(13) TF_R(15) TF_R(26) TF_R(6)
  x0 += k2; x1 += k0 + 5u;
#undef TF_R
}

struct KParams {
  const float* input;
  const float* w_ih[4];
  const float* w_hh[4];
  const float* b_ih[4];
  const float* b_hh[4];
  const float* w_lin;
  const float* b_lin;
  unsigned short* hLLC;   // [8][2][32768] bf16 — LLC copy (sc0 sc1)
  unsigned short* hL2;    // [8][2][32768] bf16 — per-XCD L2 copy (sc0), data only
  uint32_t* cnt;          // [2 kinds][8 groups][8 slots] x 32-dword padding (monotone epochs)
  uint32_t* xcdtab;       // [256]
  uint32_t* initcnt;      // [1]
  float* out;             // [128][512]
  uint32_t mk[4][2];      // per-layer threefry subkeys (partitionable split)
};

__device__ __forceinline__ unsigned short f2bf(float v) {
  uint32_t u = __float_as_uint(v);
  u += 0x7FFFu + ((u >> 16) & 1u);      // RNE
  return (unsigned short)(u >> 16);
}
__device__ __forceinline__ float bf2f(unsigned short b) {
  return __uint_as_float(((uint32_t)b) << 16);
}
__device__ __forceinline__ float sigm(float x) { return 1.f / (1.f + __expf(-x)); }
__device__ __forceinline__ float tanh_fast(float x) {
  float a = fabsf(x);
  float e = __expf(-2.f * a);
  float r = (1.f - e) / (1.f + e);
  return copysignf(r, x);
}

#define MFMA(A, Bv, C) __builtin_amdgcn_mfma_f32_32x32x16_bf16((A), (Bv), (C), 0, 0, 0)

// counted vmcnt wait (a = pipeline iterations still allowed in flight; 2 loads/iter)
__device__ __forceinline__ void vmwait_dyn(int a) {
  switch (a) {
    case 0: asm volatile("s_waitcnt vmcnt(0)" ::: "memory"); break;
    case 1: asm volatile("s_waitcnt vmcnt(2)" ::: "memory"); break;
    case 2: asm volatile("s_waitcnt vmcnt(4)" ::: "memory"); break;
    case 3: asm volatile("s_waitcnt vmcnt(6)" ::: "memory"); break;
    case 4: asm volatile("s_waitcnt vmcnt(8)" ::: "memory"); break;
    case 5: asm volatile("s_waitcnt vmcnt(10)" ::: "memory"); break;
    case 6: asm volatile("s_waitcnt vmcnt(12)" ::: "memory"); break;
    default: asm volatile("s_waitcnt vmcnt(14)" ::: "memory"); break;
  }
  __builtin_amdgcn_sched_barrier(0);
}

#define ISSUE_LLC(s0, s1, ptr) \
  asm volatile("global_load_dwordx4 %0, %2, off sc0 sc1\n\t" \
               "global_load_dwordx4 %1, %2, off offset:1024 sc0 sc1" \
               : "=&v"(s0), "=&v"(s1) : "v"(ptr) : "memory")
#define ISSUE_L2(s0, s1, ptr) \
  asm volatile("global_load_dwordx4 %0, %2, off sc0\n\t" \
               "global_load_dwordx4 %1, %2, off offset:1024 sc0" \
               : "=&v"(s0), "=&v"(s1) : "v"(ptr) : "memory")

// 8-iteration GEMM half: frags FRAGBASE..FRAGBASE+7, fully software-pipelined.
// PRECONDITION: vmcnt == 0 on entry (counted waits assume only our loads in flight).
template <int FRAGBASE, bool L2MODE>
__device__ __forceinline__ void gemm8(const unsigned short* buf,
                                      const s16x8 (&Whi)[2][16], const s16x8 (&Wlo)[2][16],
                                      int wave, int lane,
                                      f32x16& a00, f32x16& a01, f32x16& a10, f32x16& a11) {
  s16x8 st[8][2];
  const int lofs = wave * 1024 + lane * 8;   // blk = i*4 + wave
#pragma unroll
  for (int i = 0; i < 8; ++i) {
    const unsigned short* ptr = buf + i * 4096 + lofs;
    if constexpr (L2MODE) { ISSUE_L2(st[i][0], st[i][1], ptr); }
    else                  { ISSUE_LLC(st[i][0], st[i][1], ptr); }
  }
#pragma unroll
  for (int i = 0; i < 8; ++i) {
    vmwait_dyn(7 - i);
    s16x8 bh0 = st[i][0];
    s16x8 bh1 = st[i][1];
    a00 = MFMA(Whi[0][FRAGBASE + i], bh0, a00);
    a10 = MFMA(Whi[1][FRAGBASE + i], bh0, a10);
    a01 = MFMA(Whi[0][FRAGBASE + i], bh1, a01);
    a11 = MFMA(Whi[1][FRAGBASE + i], bh1, a11);
    a00 = MFMA(Wlo[0][FRAGBASE + i], bh0, a00);
    a10 = MFMA(Wlo[1][FRAGBASE + i], bh0, a10);
    a01 = MFMA(Wlo[0][FRAGBASE + i], bh1, a01);
    a11 = MFMA(Wlo[1][FRAGBASE + i], bh1, a11);
  }
}

// single-dword monotone-counter poll (all lanes same address -> 1 LLC transaction/iter)
__device__ __forceinline__ void pollcnt(const uint32_t* p, uint32_t tgt, bool slp) {
  while (__hip_atomic_load(p, __ATOMIC_RELAXED, __HIP_MEMORY_SCOPE_AGENT) < tgt) {
    if (slp) __builtin_amdgcn_s_sleep(1);
  }
}
__device__ __forceinline__ uint32_t tgt_of(int T) { return 32u * ((uint32_t)(T >> 3) + 1u); }

__global__ __launch_bounds__(256, 1) void lstm4(KParams P) {
  const int wg   = blockIdx.x;
  const int grp  = wg & 7;       // (layer, half) — one XCD per group under round-robin
  const int iwg  = wg >> 3;      // 0..31: which 16-unit slice
  const int l    = grp >> 1;
  const int p    = grp & 1;
  const int tid  = threadIdx.x;
  const int wave = tid >> 6;
  const int lane = tid & 63;

  __shared__ float part[4][64][64];   // 64 KB
  __shared__ float bias_s[64];
  __shared__ float wih1_s[64];
  __shared__ float wlin_s[16];
  __shared__ float red_s[4][64];
  __shared__ uint32_t xs[8];
  __shared__ uint32_t barflag;

  // counter addressing: kind 0 = stores-done(ST), kind 1 = reads-done(RD)
  uint32_t* const cb = P.cnt;
#define CNT(kind, g, slot) (cb + (((kind) * 8 + (g)) * 8 + (slot)) * 32)

  // ---- XCD identity probe
  uint32_t xcd;
  asm volatile("s_getreg_b32 %0, hwreg(20, 0, 4)" : "=s"(xcd));
  if (tid == 0) {
    __hip_atomic_store(&P.xcdtab[wg], xcd, __ATOMIC_RELAXED, __HIP_MEMORY_SCOPE_AGENT);
    asm volatile("s_waitcnt vmcnt(0)" ::: "memory");
    __hip_atomic_fetch_add(P.initcnt, 1u, __ATOMIC_RELAXED, __HIP_MEMORY_SCOPE_AGENT);
  }

  // ---- weight fragments (hi + lo bf16) into registers
  s16x8 Whi[2][16], Wlo[2][16];
  {
#pragma unroll
    for (int ji = 0; ji < 16; ++ji) {
      const bool valid = (l > 0) || (ji < 8);
      const float* wsrc = (l == 0 || ji >= 8) ? P.w_hh[l] : P.w_ih[l];
      const int blk = (ji & 7) * 4 + wave;
      const int col = blk * 16 + (lane >> 5) * 8;
#pragma unroll
      for (int m = 0; m < 2; ++m) {
        const int rl = m * 32 + (lane & 31);
        const int grow = (rl >> 4) * 512 + iwg * 16 + (rl & 15);
        s16x8 h8 = {0, 0, 0, 0, 0, 0, 0, 0};
        s16x8 l8 = {0, 0, 0, 0, 0, 0, 0, 0};
        if (valid) {
          const float* s = wsrc + grow * 512 + col;
#pragma unroll
          for (int e = 0; e < 8; ++e) {
            float v = s[e];
            unsigned short hb = f2bf(v);
            h8[e] = (short)hb;
            l8[e] = (short)f2bf(v - bf2f(hb));
          }
        }
        Whi[m][ji] = h8;
        Wlo[m][ji] = l8;
      }
    }
  }
  if (tid < 64) {
    const int rl = tid;
    const int grow = (rl >> 4) * 512 + iwg * 16 + (rl & 15);
    bias_s[rl] = P.b_ih[l][grow] + P.b_hh[l][grow];
    wih1_s[rl] = (l == 0) ? P.w_ih[0][grow] : 0.f;
  }
  if (l == 3 && tid < 16) wlin_s[tid] = P.w_lin[iwg * 16 + tid];

  // ---- bounded grid init barrier (timeout -> LLC-only fallback, never hang)
  if (tid == 0) {
    uint32_t okv = 1u, tries = 0u;
    while (__hip_atomic_load(P.initcnt, __ATOMIC_RELAXED, __HIP_MEMORY_SCOPE_AGENT) < 256u) {
      __builtin_amdgcn_s_sleep(8);
      if (++tries > (1u << 17)) { okv = 0u; break; }
    }
    barflag = okv;
  }
  __syncthreads();
  const bool bar_ok = (barflag != 0u);

  // ---- XCD-mapping verification
  uint32_t va = __hip_atomic_load(&P.xcdtab[tid], __ATOMIC_RELAXED, __HIP_MEMORY_SCOPE_AGENT);
  uint32_t vb = __hip_atomic_load(&P.xcdtab[tid & 7], __ATOMIC_RELAXED, __HIP_MEMORY_SCOPE_AGENT);
  int ok1 = __syncthreads_and((va == vb) ? 1 : 0);
  if (tid < 8) xs[tid] = vb;
  __syncthreads();
  bool dis = true;
#pragma unroll
  for (int a = 0; a < 8; ++a)
#pragma unroll
    for (int b = a + 1; b < 8; ++b)
      if (xs[a] == xs[b]) dis = false;
  const bool l2ok = bar_ok && (ok1 != 0) && dis;
  __syncthreads();

  const int gb = p * 64 + lane;
  const uint32_t kk0 = P.mk[l][0], kk1 = P.mk[l][1];
  float cst[4] = {0.f, 0.f, 0.f, 0.f};

  for (int t = 0; t < TT; ++t) {
    float xin = 0.f;
    if (l == 0) xin = P.input[gb * 512 + t];

    f32x16 a00 = {0,0,0,0,0,0,0,0,0,0,0,0,0,0,0,0};
    f32x16 a01 = {0,0,0,0,0,0,0,0,0,0,0,0,0,0,0,0};
    f32x16 a10 = {0,0,0,0,0,0,0,0,0,0,0,0,0,0,0,0};
    f32x16 a11 = {0,0,0,0,0,0,0,0,0,0,0,0,0,0,0,0};

    const unsigned short* pB    = P.hLLC + (size_t)(((l - 1) * 2 + p) * 2 + (t & 1)) * 32768;
    const unsigned short* pOL2  = P.hL2  + (size_t)(grp * 2 + ((t - 1) & 1)) * 32768;
    const unsigned short* pOLLC = P.hLLC + (size_t)(grp * 2 + ((t - 1) & 1)) * 32768;

    // ---- phase A: below-half GEMM (cross-layer edge, has pipeline slack)
    if (l > 0) {
      pollcnt(CNT(0, grp - 2, t & 7), tgt_of(t), true);
      asm volatile("s_waitcnt vmcnt(0)" ::: "memory");
      gemm8<0, false>(pB, Whi, Wlo, wave, lane, a00, a01, a10, a11);
    }
    // ---- phase B: own-half GEMM (critical recurrent edge; wait hidden under phase A)
    if (t > 0) {
      pollcnt(CNT(0, grp, (t - 1) & 7), tgt_of(t - 1), false);
      asm volatile("s_waitcnt vmcnt(0)" ::: "memory");
      if (l > 0) {
        if (l2ok) gemm8<8, true >(pOL2,  Whi, Wlo, wave, lane, a00, a01, a10, a11);
        else      gemm8<8, false>(pOLLC, Whi, Wlo, wave, lane, a00, a01, a10, a11);
      } else {
        if (l2ok) gemm8<0, true >(pOL2,  Whi, Wlo, wave, lane, a00, a01, a10, a11);
        else      gemm8<0, false>(pOLLC, Whi, Wlo, wave, lane, a00, a01, a10, a11);
      }
    }

    // ---- single-phase cross-wave k-split reduction ----
#pragma unroll
    for (int r = 0; r < 16; ++r) {
      const int row = (r & 3) + 8 * (r >> 2) + 4 * (lane >> 5);
      const int cl = lane & 31;
      part[wave][row][cl]           = a00[r];
      part[wave][row][32 + cl]      = a01[r];
      part[wave][32 + row][cl]      = a10[r];
      part[wave][32 + row][32 + cl] = a11[r];
    }

    // dropout factors (threefry) in the barrier shadow
    float fac[4];
#pragma unroll
    for (int cc = 0; cc < 4; ++cc) {
      const int gu = iwg * 16 + wave * 4 + cc;
      uint32_t j = ((uint32_t)t * 128u + (uint32_t)gb) * 512u + (uint32_t)gu;
      uint32_t x0 = 0u, x1 = j;
      tf2x32(kk0, kk1, x0, x1);
      fac[cc] = ((x0 ^ x1) & 0x80000000u) ? 0.f : 2.f;
    }
    __syncthreads();
    // reads-done publish: all waves' GEMM loads retired (each gemm8 ends at vmcnt(0))
    if (tid == 0 && l > 0)
      __hip_atomic_fetch_add(CNT(1, grp, t & 7), 1u, __ATOMIC_RELAXED, __HIP_MEMORY_SCOPE_AGENT);

    float si[4], sf[4], sg[4], so[4];
#pragma unroll
    for (int cc = 0; cc < 4; ++cc) {
      const int ul = wave * 4 + cc;
      si[cc] = part[0][ul][lane]      + part[1][ul][lane]      + part[2][ul][lane]      + part[3][ul][lane];
      sf[cc] = part[0][16 + ul][lane] + part[1][16 + ul][lane] + part[2][16 + ul][lane] + part[3][16 + ul][lane];
      sg[cc] = part[0][32 + ul][lane] + part[1][32 + ul][lane] + part[2][32 + ul][lane] + part[3][32 + ul][lane];
      so[cc] = part[0][48 + ul][lane] + part[1][48 + ul][lane] + part[2][48 + ul][lane] + part[3][48 + ul][lane];
    }

    // ---- elementwise LSTM cell ----
    float osum = 0.f;
    u16x4 hv;
#pragma unroll
    for (int cc = 0; cc < 4; ++cc) {
      const int ul = wave * 4 + cc;
      float pi = si[cc] + bias_s[ul];
      float pf = sf[cc] + bias_s[16 + ul];
      float pg = sg[cc] + bias_s[32 + ul];
      float po = so[cc] + bias_s[48 + ul];
      if (l == 0) {
        pi += wih1_s[ul] * xin;
        pf += wih1_s[16 + ul] * xin;
        pg += wih1_s[32 + ul] * xin;
        po += wih1_s[48 + ul] * xin;
      }
      float ig = sigm(pi), fg = sigm(pf), gg = tanh_fast(pg), og = sigm(po);
      float cn = fg * cst[cc] + ig * gg;
      cst[cc] = cn;
      float hh = og * tanh_fast(cn) * fac[cc];
      hv[cc] = f2bf(hh);
      if (l == 3) osum += hh * wlin_s[ul];
    }

    // ---- eviction guard: layer-above must have finished reading hLLC slot (t-2)
    if (l < 3 && t >= 2)
      pollcnt(CNT(1, grp + 2, (t - 2) & 7), tgt_of(t - 2), true);

    // ---- h stores + drain + publish stores-done counter
    {
      const int elem = ((iwg * 2 + (lane >> 5)) * 64 + (wave >> 1) * 32 + (lane & 31)) * 8 + (wave & 1) * 4;
      unsigned short* wLLC = P.hLLC + (size_t)(grp * 2 + (t & 1)) * 32768 + elem;
      unsigned short* wL2  = P.hL2  + (size_t)(grp * 2 + (t & 1)) * 32768 + elem;
      if (l < 3 || !l2ok) {
        asm volatile("global_store_dwordx2 %0, %1, off sc0 sc1" :: "v"(wLLC), "v"(hv) : "memory");
      }
      if (l2ok) {
        asm volatile("global_store_dwordx2 %0, %1, off sc0" :: "v"(wL2), "v"(hv) : "memory");
      }
      asm volatile("s_waitcnt vmcnt(0)" ::: "memory");
    }
    __syncthreads();
    if (tid == 0)
      __hip_atomic_fetch_add(CNT(0, grp, t & 7), 1u, __ATOMIC_RELAXED, __HIP_MEMORY_SCOPE_AGENT);

    // ---- layer-3 projection (after publish)
    if (l == 3) {
      red_s[wave][lane] = osum;
      __syncthreads();
      if (tid < 64) {
        float v = red_s[0][tid] + red_s[1][tid] + red_s[2][tid] + red_s[3][tid];
        if (iwg == 0) v += P.b_lin[0];
        atomicAdd(&P.out[(p * 64 + tid) * 512 + t], v);
      }
    }
  }
#undef CNT
}

extern "C" void kernel_launch(void* const* d_in, const int* in_sizes, int n_in,
                              void* d_out, int out_size, void* d_ws, size_t ws_size,
                              hipStream_t stream) {
  (void)in_sizes; (void)n_in; (void)ws_size;
  KParams P;
  P.input = (const float*)d_in[0];
  for (int l = 0; l < 4; ++l) {
    P.w_ih[l] = (const float*)d_in[1 + 4 * l];
    P.w_hh[l] = (const float*)d_in[2 + 4 * l];
    P.b_ih[l] = (const float*)d_in[3 + 4 * l];
    P.b_hh[l] = (const float*)d_in[4 + 4 * l];
  }
  P.w_lin = (const float*)d_in[17];
  P.b_lin = (const float*)d_in[18];
  unsigned char* ws = (unsigned char*)d_ws;
  P.hLLC    = (unsigned short*)(ws);                          // 1 MB   [8][2][32768]
  P.hL2     = (unsigned short*)(ws + (1u << 20));             // 1 MB   [8][2][32768]
  P.cnt     = (uint32_t*)(ws + (2u << 20));                   // 16 KB  [2][8][8] x 128B
  P.xcdtab  = (uint32_t*)(ws + (2u << 20) + (16u << 10));     // 1 KB
  P.initcnt = (uint32_t*)(ws + (2u << 20) + (16u << 10) + 1024);
  P.out     = (float*)d_out;
  // total ws span ~2.02 MB (<= 2.62 MB proven by R2/R3)

  // subkeys = jax.random.split(key(42), 4) under threefry_partitionable=True
  for (uint32_t i = 0; i < 4; ++i) {
    uint32_t x0 = 0u, x1 = i;
    tf2x32(0u, 42u, x0, x1);
    P.mk[i][0] = x0; P.mk[i][1] = x1;
  }

  hipMemsetAsync(P.cnt, 0, 2 * 8 * 8 * 32 * sizeof(uint32_t), stream);
  hipMemsetAsync(P.xcdtab, 0, 2048, stream);                  // xcdtab + initcnt
  hipMemsetAsync(d_out, 0, (size_t)out_size * sizeof(float), stream);
  hipLaunchKernelGGL(lstm4, dim3(256), dim3(256), 0, stream, P);
}